// Round 2
// baseline (458.746 us; speedup 1.0000x reference)
//
#include <hip/hip_runtime.h>
#include <hip/hip_bf16.h>

// Problem constants (B=2, S=2048, H=2048, NH=16, HD=128)
#define B_SZ 2
#define S_LEN 2048
#define H_DIM 2048
#define N_HEAD 16
#define HD 128

using bf16 = __hip_bfloat16;
using bf16x8 = __bf16 __attribute__((ext_vector_type(8)));
using floatx4 = float __attribute__((ext_vector_type(4)));

typedef unsigned int __attribute__((address_space(1))) as1_uint;
typedef unsigned int __attribute__((address_space(3))) as3_uint;

// async global->LDS, 16B per lane. LDS dest = wave-uniform base + lane*16.
__device__ inline void async_load16(const void* g, void* l) {
  __builtin_amdgcn_global_load_lds((const as1_uint*)g, (as3_uint*)l, 16, 0, 0);
}

__device__ inline void store_out(float* p, float v) { *p = v; }
__device__ inline void store_out(bf16* p, float v) { *p = __float2bfloat16(v); }

// ---------------- fp32 -> bf16 cast (4 elems/thread) ----------------
__global__ __launch_bounds__(256) void cast_kernel(const float* __restrict__ in,
                                                   bf16* __restrict__ out, int n4) {
  int i = blockIdx.x * 256 + threadIdx.x;
  if (i >= n4) return;
  const float4 v = ((const float4*)in)[i];
  union { bf16 h[4]; uint2 u; } o;
  o.h[0] = __float2bfloat16(v.x);
  o.h[1] = __float2bfloat16(v.y);
  o.h[2] = __float2bfloat16(v.z);
  o.h[3] = __float2bfloat16(v.w);
  ((uint2*)out)[i] = o.u;
}

// fused cast of the 4 weight matrices (1M float4-groups each)
__global__ __launch_bounds__(256) void cast4_kernel(
    const float* __restrict__ a, const float* __restrict__ b,
    const float* __restrict__ c, const float* __restrict__ d,
    bf16* __restrict__ oa, bf16* __restrict__ ob,
    bf16* __restrict__ oc, bf16* __restrict__ od) {
  int i = blockIdx.x * 256 + threadIdx.x;
  int sel = i >> 20;
  int j = i & 0xFFFFF;
  const float* src = sel == 0 ? a : sel == 1 ? b : sel == 2 ? c : d;
  bf16* dst = sel == 0 ? oa : sel == 1 ? ob : sel == 2 ? oc : od;
  const float4 v = ((const float4*)src)[j];
  union { bf16 h[4]; uint2 u; } o;
  o.h[0] = __float2bfloat16(v.x);
  o.h[1] = __float2bfloat16(v.y);
  o.h[2] = __float2bfloat16(v.z);
  o.h[3] = __float2bfloat16(v.w);
  ((uint2*)dst)[j] = o.u;
}

// ---------------- C[M][N] = A[M][K] * B[N][K]^T  (m97-style, proven) ----------
template <typename OutT>
__global__ __launch_bounds__(256) void gemm_bt(const bf16* __restrict__ A,
                                               const bf16* __restrict__ B,
                                               OutT* __restrict__ C,
                                               int M, int N, int K) {
  __shared__ alignas(16) bf16 As[128 * 32];
  __shared__ alignas(16) bf16 Bs[128 * 32];
  const int tid = threadIdx.x;
  const int wave = tid >> 6;
  const int lane = tid & 63;
  const int quad = lane >> 4;
  const int l16 = lane & 15;
  const int m0 = blockIdx.x * 128;
  const int n0 = blockIdx.y * 128;
  const int wm = (wave >> 1) * 64;
  const int wn = (wave & 1) * 64;

  const bf16* Ag = A + (size_t)(m0 + (tid >> 2)) * K + (tid & 3) * 8;
  const bf16* Bg = B + (size_t)(n0 + (tid >> 2)) * K + (tid & 3) * 8;
  char* AsB = (char*)As + wave * 1024;
  char* BsB = (char*)Bs + wave * 1024;
  const size_t rowskip = (size_t)64 * K;

  floatx4 acc[4][4] = {};

  for (int k0 = 0; k0 < K; k0 += 32) {
    async_load16(Ag + k0, AsB);
    async_load16(Ag + rowskip + k0, AsB + 4096);
    async_load16(Bg + k0, BsB);
    async_load16(Bg + rowskip + k0, BsB + 4096);
    __syncthreads();

    bf16x8 af[4], bfr[4];
#pragma unroll
    for (int i = 0; i < 4; i++)
      af[i] = *(const bf16x8*)&As[(wm + i * 16 + l16) * 32 + quad * 8];
#pragma unroll
    for (int j = 0; j < 4; j++)
      bfr[j] = *(const bf16x8*)&Bs[(wn + j * 16 + l16) * 32 + quad * 8];
#pragma unroll
    for (int i = 0; i < 4; i++)
#pragma unroll
      for (int j = 0; j < 4; j++)
        acc[i][j] = __builtin_amdgcn_mfma_f32_16x16x32_bf16(af[i], bfr[j], acc[i][j], 0, 0, 0);
    __syncthreads();
  }

  // C/D layout: col = lane&15, row = quad*4 + reg
#pragma unroll
  for (int i = 0; i < 4; i++) {
    const int row = m0 + wm + i * 16 + quad * 4;
#pragma unroll
    for (int j = 0; j < 4; j++) {
      const int col = n0 + wn + j * 16 + l16;
#pragma unroll
      for (int r = 0; r < 4; r++)
        store_out(&C[(size_t)(row + r) * N + col], acc[i][j][r]);
    }
  }
}

// ---- 256x256-tile 8-wave 4-phase pipelined QK-proj GEMM with fused RoPE ----
// A[4096][2048] bf16, B[4096][2048] bf16 (B^T GEMM), C = RoPE(A*B^T) [4096][4096].
// BK=64, double-buffered LDS (2 x (A 32KB + B 32KB) = 128KB, 1 block/CU).
// Staging via global_load_lds with XOR-pre-swizzled global source column
// (col ^= (row&7)<<4, an involution) so ds_read_b128 of stride-128B rows is
// conflict-free (T2, rule #21: linear dest + inv-swz source + swz read).
// Schedule (T3+T4+T5): 4 phases per K-tile, each {ds_read batch | stage-issue
// -> barrier -> lgkmcnt(0) -> setprio(1) 16xMFMA setprio(0) -> barrier}.
// Tile t+2's 8 loads are issued into the CURRENT buffer at P2/P3 (its reads
// all drained by P1's lgkmcnt(0)+barrier), so the boundary wait is a counted
// vmcnt(8) -- loads stay in flight across barriers; never 0 in steady state.
__global__ __launch_bounds__(512, 2) void gemm_qk_rope256(
    const bf16* __restrict__ A, const bf16* __restrict__ B,
    bf16* __restrict__ C, const float* __restrict__ cosT,
    const float* __restrict__ sinT, const int* __restrict__ pos) {
  __shared__ alignas(16) char lds[131072];
  const int tid = threadIdx.x;
  const int wv = tid >> 6;
  const int lane = tid & 63;
  const int quad = lane >> 4;
  const int l16 = lane & 15;
  const int lrow = lane >> 3;                       // 0..7: staging row within wave-chunk
  const int scol = ((lane & 7) << 4) ^ (lrow << 4); // pre-swizzled global col byte

  // bijective chunked XCD swizzle: 256 wgs, 8 XCDs -> each XCD gets 2 row-panels
  const int id = blockIdx.x;
  const int swz = (id & 7) * 32 + (id >> 3);
  const int m0 = (swz >> 4) * 256;
  const int n0 = (swz & 15) * 256;
  const int wrow = (wv >> 1) * 64;   // 4 waves down
  const int wcol = (wv & 1) * 128;   // 2 waves across (full head-half per wave)

  const char* Ag = (const char*)A + (size_t)(m0 + wv * 8 + lrow) * 4096 + scol;
  const char* Bg = (const char*)B + (size_t)(n0 + wv * 8 + lrow) * 4096 + scol;
  char* const ldsW = (char*)lds + wv * 1024;  // wave-uniform LDS staging base

  const int csw0 = (quad << 4) ^ ((l16 & 7) << 4);  // swizzled read col, ks=0
  const int csw1 = csw0 ^ 64;                       // ks=1 (bit6 flip commutes w/ XOR)

  floatx4 acc[4][8] = {};
  bf16x8 af[4][2], bfr[8][2];

#define STAGE_A256(kt, buf) { \
    const char* s_ = Ag + (size_t)(kt) * 128; \
    char* d_ = ldsW + (buf) * 65536; \
    async_load16(s_, d_); \
    async_load16(s_ + (size_t)64 * 4096, d_ + 64 * 128); \
    async_load16(s_ + (size_t)128 * 4096, d_ + 128 * 128); \
    async_load16(s_ + (size_t)192 * 4096, d_ + 192 * 128); }
#define STAGE_B256(kt, buf) { \
    const char* s_ = Bg + (size_t)(kt) * 128; \
    char* d_ = ldsW + (buf) * 65536 + 32768; \
    async_load16(s_, d_); \
    async_load16(s_ + (size_t)64 * 4096, d_ + 64 * 128); \
    async_load16(s_ + (size_t)128 * 4096, d_ + 128 * 128); \
    async_load16(s_ + (size_t)192 * 4096, d_ + 192 * 128); }
#define READ_A256(I) { \
    const char* p_ = cA + (wrow + (I) * 16 + l16) * 128; \
    af[I][0] = *(const bf16x8*)(p_ + csw0); \
    af[I][1] = *(const bf16x8*)(p_ + csw1); }
#define READ_B256(J) { \
    const char* p_ = cB + (wcol + (J) * 16 + l16) * 128; \
    bfr[J][0] = *(const bf16x8*)(p_ + csw0); \
    bfr[J][1] = *(const bf16x8*)(p_ + csw1); }
#define MFMA_Q256(I0, J0) { \
    _Pragma("unroll") for (int ks = 0; ks < 2; ++ks) \
    _Pragma("unroll") for (int di = 0; di < 2; ++di) \
    _Pragma("unroll") for (int dj = 0; dj < 4; ++dj) \
      acc[(I0) + di][(J0) + dj] = __builtin_amdgcn_mfma_f32_16x16x32_bf16( \
          af[(I0) + di][ks], bfr[(J0) + dj][ks], acc[(I0) + di][(J0) + dj], 0, 0, 0); }

  // prologue: stage tile0 -> buf0, tile1 -> buf1; wait tile0 (8 newest in flight)
  STAGE_A256(0, 0) STAGE_B256(0, 0)
  STAGE_A256(1, 1) STAGE_B256(1, 1)
  asm volatile("s_waitcnt vmcnt(8)" ::: "memory");
  __builtin_amdgcn_s_barrier();

  const int NT = 32;  // K=2048 / BK=64
  for (int t = 0; t < NT; ++t) {
    const char* cA = (const char*)lds + (t & 1) * 65536;
    const char* cB = cA + 32768;
    // ---- P0: quadrant (rows 0-1, cols 0-3)
    READ_A256(0) READ_A256(1)
    READ_B256(0) READ_B256(1) READ_B256(2) READ_B256(3)
    __builtin_amdgcn_s_barrier();
    asm volatile("s_waitcnt lgkmcnt(0)" ::: "memory");
    __builtin_amdgcn_sched_barrier(0);
    __builtin_amdgcn_s_setprio(1);
    MFMA_Q256(0, 0)
    __builtin_amdgcn_s_setprio(0);
    __builtin_amdgcn_s_barrier();
    // ---- P1: quadrant (rows 2-3, cols 0-3)
    READ_A256(2) READ_A256(3)
    READ_B256(4) READ_B256(5) READ_B256(6) READ_B256(7)
    __builtin_amdgcn_s_barrier();
    asm volatile("s_waitcnt lgkmcnt(0)" ::: "memory");
    __builtin_amdgcn_sched_barrier(0);
    __builtin_amdgcn_s_setprio(1);
    MFMA_Q256(2, 0)
    __builtin_amdgcn_s_setprio(0);
    __builtin_amdgcn_s_barrier();
    // all reads of buffer (t&1) are drained (lgkmcnt(0) above) and all waves
    // passed that point (barrier above) -> safe to overwrite it now.
    __builtin_amdgcn_sched_barrier(0);
    asm volatile("" ::: "memory");
    // ---- P2: quadrant (rows 0-1, cols 4-7); issue tile t+2's A halves
    if (t + 2 < NT) { STAGE_A256(t + 2, t & 1) }
    __builtin_amdgcn_s_setprio(1);
    MFMA_Q256(0, 4)
    __builtin_amdgcn_s_setprio(0);
    __builtin_amdgcn_s_barrier();
    // ---- P3: quadrant (rows 2-3, cols 4-7); issue tile t+2's B halves
    if (t + 2 < NT) { STAGE_B256(t + 2, t & 1) }
    __builtin_amdgcn_s_setprio(1);
    MFMA_Q256(2, 4)
    __builtin_amdgcn_s_setprio(0);
    // boundary: wait tile t+1 landed; keep tile t+2's 8 loads in flight
    if (t + 2 < NT) {
      asm volatile("s_waitcnt vmcnt(8)" ::: "memory");
    } else {
      asm volatile("s_waitcnt vmcnt(0)" ::: "memory");
    }
    __builtin_amdgcn_s_barrier();
  }

  // epilogue: RoPE on (d, d+64) pairs (wave strip is a full 128-wide head-half)
  const float sc = ((n0 + wcol) < 2048) ? 0.08838834764831845f : 1.0f;  // 1/sqrt(128) on Q
#pragma unroll
  for (int i = 0; i < 4; ++i) {
#pragma unroll
    for (int r = 0; r < 4; ++r) {
      const int row = m0 + wrow + i * 16 + quad * 4 + r;
      const int p = pos[row];
      const float* cp = cosT + (size_t)p * HD;
      const float* sp = sinT + (size_t)p * HD;
      bf16* Crow = C + (size_t)row * 4096 + n0 + wcol + l16;
#pragma unroll
      for (int j = 0; j < 4; ++j) {
        const int d = j * 16 + l16;
        const float c = cp[d], s = sp[d];
        const float v1 = acc[i][j][r], v2 = acc[i][j + 4][r];
        Crow[j * 16] = __float2bfloat16((v1 * c - v2 * s) * sc);
        Crow[j * 16 + 64] = __float2bfloat16((v2 * c + v1 * s) * sc);
      }
    }
  }
}

// ---------------- flash attention v2: 256-q-row blocks, 8 waves ----------------
// grid = (B*NH, S/256), 512 threads. Q-tile 256 rows (wave strip = 32 rows).
// LDS: K [128 kv][128 d] 32KB + V^T [128 d][128 kv] 32KB + P (per-wave 32x128)
// 64KB = 128KB total, 1 block/CU, 8 waves.
// T2: stride-256B rows + XOR swizzle (byte ^= (row&7)<<4) on K/V/P; reg-staged
// so both write and read sides swizzle (rule #21 both-sides-or-neither).
// T14: tile t+1's 8x16B global loads issued at top of iteration t (in flight
// under QK^T+softmax+PV), ds_write after the post-PV barrier.
// P has its own buffer (per-wave private) -> only 2 barriers/iter; waves drift
// -> T5 setprio has roles to arbitrate.
// Fixed-shift softmax kept: p = exp(s - 12), one butterfly reduce at the end.
__global__ __launch_bounds__(512, 2) void flash_attn(
    const bf16* __restrict__ QK, const bf16* __restrict__ Vt,
    const float* __restrict__ mask, bf16* __restrict__ AO) {
  __shared__ alignas(16) bf16 Ks[128 * 128];      // 32KB, K tile [k_pos][d]
  __shared__ alignas(16) bf16 Vs[128 * 128];      // 32KB, V^T tile [d][k_pos]
  __shared__ alignas(16) bf16 Ps[8 * 32 * 128];   // 64KB, per-wave P [q][k]
  const int tid = threadIdx.x;
  const int wv = tid >> 6;
  const int lane = tid & 63;
  const int quad = lane >> 4;
  const int l16 = lane & 15;
  const int b = blockIdx.x >> 4;
  const int h = blockIdx.x & 15;
  const int q0 = blockIdx.y * 256;

  const bf16* Qb = QK + (size_t)(b * S_LEN + q0) * 4096 + h * HD;
  const char* Kb = (const char*)(QK + (size_t)(b * S_LEN) * 4096 + 2048 + h * HD);
  const char* Vb = (const char*)(Vt + (size_t)(h * HD) * 4096 + (size_t)b * S_LEN);
  const float* Mb = mask + b * S_LEN;

  // staging geometry: [128][128] tile = 2048 16B-chunks; 512 thr x 4 chunks
  const int srow = tid >> 4;           // + j*32 -> rows 0..127
  const int scol = (tid & 15) * 16;    // byte col within 256B row
  const int kswz = (l16 & 7) << 4;     // read-side row swizzle (row&7 == l16&7)

  // Q fragments in registers for the whole kernel. A layout: A[m=l16][k=quad*8+j]
  bf16x8 qf[2][4];
#pragma unroll
  for (int s = 0; s < 2; s++)
#pragma unroll
    for (int kc = 0; kc < 4; kc++)
      qf[s][kc] = *(const bf16x8*)(Qb + (size_t)(wv * 32 + s * 16 + l16) * 4096 +
                                   kc * 32 + quad * 8);

  uint4 kreg[4], vreg[4];
#define FA_LOAD_TILES(k0_) { \
    const char* kb_ = Kb + (size_t)(k0_) * 8192; \
    const char* vb_ = Vb + (size_t)(k0_) * 2; \
    _Pragma("unroll") for (int j = 0; j < 4; ++j) { \
      const int r_ = srow + j * 32; \
      kreg[j] = *(const uint4*)(kb_ + (size_t)r_ * 8192 + scol); \
      vreg[j] = *(const uint4*)(vb_ + (size_t)r_ * 8192 + scol); } }
#define FA_WRITE_TILES() { \
    _Pragma("unroll") for (int j = 0; j < 4; ++j) { \
      const int r_ = srow + j * 32; \
      const int c_ = scol ^ ((r_ & 7) << 4); \
      *(uint4*)((char*)Ks + r_ * 256 + c_) = kreg[j]; \
      *(uint4*)((char*)Vs + r_ * 256 + c_) = vreg[j]; } }

  float l_i[2][4] = {};
  floatx4 O[2][8] = {};

  // prologue: stage tile 0
  FA_LOAD_TILES(0)
  FA_WRITE_TILES()
  __syncthreads();

  for (int it = 0; it < 16; ++it) {
    const int k0 = it * 128;
    // T14: issue next tile's global loads now; they fly under QK^T+softmax+PV
    if (it + 1 < 16) { FA_LOAD_TILES(k0 + 128) }

    // QK^T: Sa[strip][ct] is 16x16, rows = q, cols = k_pos
    floatx4 Sa[2][8] = {};
    __builtin_amdgcn_s_setprio(1);
#pragma unroll
    for (int ct = 0; ct < 8; ct++) {
      bf16x8 kf[4];
#pragma unroll
      for (int kc = 0; kc < 4; kc++)
        kf[kc] = *(const bf16x8*)((const char*)Ks + (ct * 16 + l16) * 256 +
                                  ((kc * 64 + quad * 16) ^ kswz));
#pragma unroll
      for (int s = 0; s < 2; s++)
#pragma unroll
        for (int kc = 0; kc < 4; kc++)
          Sa[s][ct] = __builtin_amdgcn_mfma_f32_16x16x32_bf16(qf[s][kc], kf[kc], Sa[s][ct], 0, 0, 0);
    }
    __builtin_amdgcn_s_setprio(0);

    // mask bias with fixed shift folded in
    float addv[8];
#pragma unroll
    for (int ct = 0; ct < 8; ct++)
      addv[ct] = (1.0f - Mb[k0 + ct * 16 + l16]) * -10000.0f - 12.0f;

    // softmax-lite: p = exp(s + addv); write P to own wave's region (swizzled)
    char* const pwv = (char*)Ps + wv * 8192;
#pragma unroll
    for (int s = 0; s < 2; s++) {
#pragma unroll
      for (int r = 0; r < 4; r++) {
        const int lr = s * 16 + quad * 4 + r;
        char* prow = pwv + lr * 256;
        const int rsw = (lr & 7) << 4;
#pragma unroll
        for (int ct = 0; ct < 8; ct++) {
          float p = __expf(Sa[s][ct][r] + addv[ct]);
          l_i[s][r] += p;
          *(bf16*)(prow + ((ct * 32 + l16 * 2) ^ rsw)) = __float2bfloat16(p);
        }
      }
    }

    // PV: O[q][d] += P[q][k] * V[k][d]; A-frags from own wave's P (no barrier)
    __builtin_amdgcn_s_setprio(1);
#pragma unroll
    for (int kc = 0; kc < 4; kc++) {
      bf16x8 pa[2];
#pragma unroll
      for (int s = 0; s < 2; s++)
        pa[s] = *(const bf16x8*)(pwv + (s * 16 + l16) * 256 +
                                 ((kc * 64 + quad * 16) ^ kswz));
#pragma unroll
      for (int dt = 0; dt < 8; dt++) {
        bf16x8 vf = *(const bf16x8*)((const char*)Vs + (dt * 16 + l16) * 256 +
                                     ((kc * 64 + quad * 16) ^ kswz));
#pragma unroll
        for (int s = 0; s < 2; s++)
          O[s][dt] = __builtin_amdgcn_mfma_f32_16x16x32_bf16(pa[s], vf, O[s][dt], 0, 0, 0);
      }
    }
    __builtin_amdgcn_s_setprio(0);
    __syncthreads();  // all waves' K/V reads of this tile done

    if (it + 1 < 16) {
      FA_WRITE_TILES()   // vmcnt waits inserted by compiler on kreg/vreg deps
      __syncthreads();   // staged tile visible to all waves
    }
  }

  // one-time cross-lane reduction of l over the 16 k-lanes (l16 bits 1,2,4,8)
#pragma unroll
  for (int s = 0; s < 2; s++)
#pragma unroll
    for (int r = 0; r < 4; r++)
#pragma unroll
      for (int off = 1; off < 16; off <<= 1)
        l_i[s][r] += __shfl_xor(l_i[s][r], off);

  // epilogue: O /= l, write AO [b, s, h*128+d] (stride H_DIM)
#pragma unroll
  for (int s = 0; s < 2; s++) {
    const int qrow = q0 + wv * 32 + s * 16 + quad * 4;
#pragma unroll
    for (int r = 0; r < 4; r++) {
      float inv = 1.0f / l_i[s][r];
      bf16* outp = AO + (size_t)(b * S_LEN + qrow + r) * H_DIM + h * HD + l16;
#pragma unroll
      for (int dt = 0; dt < 8; dt++)
        outp[dt * 16] = __float2bfloat16(O[s][dt][r] * inv);
    }
  }
}

// ---------------- launch ----------------
extern "C" void kernel_launch(void* const* d_in, const int* in_sizes, int n_in,
                              void* d_out, int out_size, void* d_ws, size_t ws_size,
                              hipStream_t stream) {
  const float* hs   = (const float*)d_in[0];
  const float* wq   = (const float*)d_in[1];
  const float* wk   = (const float*)d_in[2];
  const float* wv   = (const float*)d_in[3];
  const float* wo   = (const float*)d_in[4];
  const float* cosT = (const float*)d_in[5];
  const float* sinT = (const float*)d_in[6];
  const float* mask = (const float*)d_in[7];
  const int*   pos  = (const int*)d_in[8];

  char* ws = (char*)d_ws;
  // workspace layout (96 MB total)
  bf16* Xbf  = (bf16*)ws;                        // [4096,2048] 16MB (reused as AO)
  bf16* Wqkb = (bf16*)(ws + (size_t)(16 << 20)); // [4096,2048] 16MB (Wq rows 0..2047, Wk rows 2048..)
  bf16* Wvb  = (bf16*)(ws + (size_t)(32 << 20)); // 8MB
  bf16* Wob  = (bf16*)(ws + (size_t)(40 << 20)); // 8MB
  bf16* QKm  = (bf16*)(ws + (size_t)(48 << 20)); // [4096 tok][4096] 32MB (Q|K, post-RoPE)
  bf16* Vtm  = (bf16*)(ws + (size_t)(80 << 20)); // [2048 feat][4096 tok] 16MB (V^T)
  bf16* AO   = Xbf;                              // attention output aliases Xbf (dead)

  cast_kernel<<<8192, 256, 0, stream>>>(hs, Xbf, 2097152);
  cast4_kernel<<<16384, 256, 0, stream>>>(wq, wk, wv, wo,
                                          Wqkb, Wqkb + (size_t)2048 * 2048, Wvb, Wob);

  // QK = RoPE(X [Wq;Wk]^T) fused; 256^2-tile 4-phase pipelined kernel
  gemm_qk_rope256<<<256, 512, 0, stream>>>(Xbf, Wqkb, QKm, cosT, sinT, pos);
  // Vt = Wv X^T (feature-major)
  gemm_bt<bf16><<<dim3(16, 32), 256, 0, stream>>>(Wvb, Xbf, Vtm, 2048, 4096, 2048);

  flash_attn<<<dim3(32, 8), 512, 0, stream>>>(QKm, Vtm, mask, AO);

  // out = AO Wo^T (fp32 out)
  gemm_bt<float><<<dim3(32, 16), 256, 0, stream>>>(AO, Wob, (float*)d_out, 4096, 2048, 2048);
}

// Round 4
// 437.504 us; speedup vs baseline: 1.0486x; 1.0486x over previous
//
#include <hip/hip_runtime.h>
#include <hip/hip_bf16.h>

// Problem constants (B=2, S=2048, H=2048, NH=16, HD=128)
#define B_SZ 2
#define S_LEN 2048
#define H_DIM 2048
#define N_HEAD 16
#define HD 128

using bf16 = __hip_bfloat16;
using bf16x8 = __bf16 __attribute__((ext_vector_type(8)));
using floatx4 = float __attribute__((ext_vector_type(4)));

typedef unsigned int __attribute__((address_space(1))) as1_uint;
typedef unsigned int __attribute__((address_space(3))) as3_uint;

// async global->LDS, 16B per lane. LDS dest = wave-uniform base + lane*16.
__device__ inline void async_load16(const void* g, void* l) {
  __builtin_amdgcn_global_load_lds((const as1_uint*)g, (as3_uint*)l, 16, 0, 0);
}

__device__ inline void store_out(float* p, float v) { *p = v; }
__device__ inline void store_out(bf16* p, float v) { *p = __float2bfloat16(v); }

// ---------------- fp32 -> bf16 cast (4 elems/thread) ----------------
__global__ __launch_bounds__(256) void cast_kernel(const float* __restrict__ in,
                                                   bf16* __restrict__ out, int n4) {
  int i = blockIdx.x * 256 + threadIdx.x;
  if (i >= n4) return;
  const float4 v = ((const float4*)in)[i];
  union { bf16 h[4]; uint2 u; } o;
  o.h[0] = __float2bfloat16(v.x);
  o.h[1] = __float2bfloat16(v.y);
  o.h[2] = __float2bfloat16(v.z);
  o.h[3] = __float2bfloat16(v.w);
  ((uint2*)out)[i] = o.u;
}

// fused cast of the 4 weight matrices (1M float4-groups each)
__global__ __launch_bounds__(256) void cast4_kernel(
    const float* __restrict__ a, const float* __restrict__ b,
    const float* __restrict__ c, const float* __restrict__ d,
    bf16* __restrict__ oa, bf16* __restrict__ ob,
    bf16* __restrict__ oc, bf16* __restrict__ od) {
  int i = blockIdx.x * 256 + threadIdx.x;
  int sel = i >> 20;
  int j = i & 0xFFFFF;
  const float* src = sel == 0 ? a : sel == 1 ? b : sel == 2 ? c : d;
  bf16* dst = sel == 0 ? oa : sel == 1 ? ob : sel == 2 ? oc : od;
  const float4 v = ((const float4*)src)[j];
  union { bf16 h[4]; uint2 u; } o;
  o.h[0] = __float2bfloat16(v.x);
  o.h[1] = __float2bfloat16(v.y);
  o.h[2] = __float2bfloat16(v.z);
  o.h[3] = __float2bfloat16(v.w);
  ((uint2*)dst)[j] = o.u;
}

// ---------------- C[M][N] = A[M][K] * B[N][K]^T  (m97-style, proven) ----------
template <typename OutT>
__global__ __launch_bounds__(256) void gemm_bt(const bf16* __restrict__ A,
                                               const bf16* __restrict__ B,
                                               OutT* __restrict__ C,
                                               int M, int N, int K) {
  __shared__ alignas(16) bf16 As[128 * 32];
  __shared__ alignas(16) bf16 Bs[128 * 32];
  const int tid = threadIdx.x;
  const int wave = tid >> 6;
  const int lane = tid & 63;
  const int quad = lane >> 4;
  const int l16 = lane & 15;
  const int m0 = blockIdx.x * 128;
  const int n0 = blockIdx.y * 128;
  const int wm = (wave >> 1) * 64;
  const int wn = (wave & 1) * 64;

  const bf16* Ag = A + (size_t)(m0 + (tid >> 2)) * K + (tid & 3) * 8;
  const bf16* Bg = B + (size_t)(n0 + (tid >> 2)) * K + (tid & 3) * 8;
  char* AsB = (char*)As + wave * 1024;
  char* BsB = (char*)Bs + wave * 1024;
  const size_t rowskip = (size_t)64 * K;

  floatx4 acc[4][4] = {};

  for (int k0 = 0; k0 < K; k0 += 32) {
    async_load16(Ag + k0, AsB);
    async_load16(Ag + rowskip + k0, AsB + 4096);
    async_load16(Bg + k0, BsB);
    async_load16(Bg + rowskip + k0, BsB + 4096);
    __syncthreads();

    bf16x8 af[4], bfr[4];
#pragma unroll
    for (int i = 0; i < 4; i++)
      af[i] = *(const bf16x8*)&As[(wm + i * 16 + l16) * 32 + quad * 8];
#pragma unroll
    for (int j = 0; j < 4; j++)
      bfr[j] = *(const bf16x8*)&Bs[(wn + j * 16 + l16) * 32 + quad * 8];
#pragma unroll
    for (int i = 0; i < 4; i++)
#pragma unroll
      for (int j = 0; j < 4; j++)
        acc[i][j] = __builtin_amdgcn_mfma_f32_16x16x32_bf16(af[i], bfr[j], acc[i][j], 0, 0, 0);
    __syncthreads();
  }

  // C/D layout: col = lane&15, row = quad*4 + reg
#pragma unroll
  for (int i = 0; i < 4; i++) {
    const int row = m0 + wm + i * 16 + quad * 4;
#pragma unroll
    for (int j = 0; j < 4; j++) {
      const int col = n0 + wn + j * 16 + l16;
#pragma unroll
      for (int r = 0; r < 4; r++)
        store_out(&C[(size_t)(row + r) * N + col], acc[i][j][r]);
    }
  }
}

// ---- 256x256-tile 8-wave 4-phase pipelined QK-proj GEMM with fused RoPE ----
// A[4096][2048] bf16, B[4096][2048] bf16 (B^T GEMM), C = RoPE(A*B^T) [4096][4096].
// BK=64, double-buffered LDS (2 x (A 32KB + B 32KB) = 128KB, 1 block/CU).
// Staging via global_load_lds with XOR-pre-swizzled global source column
// (col ^= (row&7)<<4, an involution) so ds_read_b128 of stride-128B rows is
// conflict-free (T2, rule #21: linear dest + inv-swz source + swz read).
// Schedule (T3+T4+T5): 4 phases per K-tile, each {ds_read batch | stage-issue
// -> barrier -> lgkmcnt(0) -> setprio(1) 16xMFMA setprio(0) -> barrier}.
// Tile t+2's 8 loads are issued into the CURRENT buffer at P2/P3 (its reads
// all drained by P1's lgkmcnt(0)+barrier), so the boundary wait is a counted
// vmcnt(8) -- loads stay in flight across barriers; never 0 in steady state.
__global__ __launch_bounds__(512, 2) void gemm_qk_rope256(
    const bf16* __restrict__ A, const bf16* __restrict__ B,
    bf16* __restrict__ C, const float* __restrict__ cosT,
    const float* __restrict__ sinT, const int* __restrict__ pos) {
  __shared__ alignas(16) char lds[131072];
  const int tid = threadIdx.x;
  const int wv = tid >> 6;
  const int lane = tid & 63;
  const int quad = lane >> 4;
  const int l16 = lane & 15;
  const int lrow = lane >> 3;                       // 0..7: staging row within wave-chunk
  const int scol = ((lane & 7) << 4) ^ (lrow << 4); // pre-swizzled global col byte

  // bijective chunked XCD swizzle: 256 wgs, 8 XCDs -> each XCD gets 2 row-panels
  const int id = blockIdx.x;
  const int swz = (id & 7) * 32 + (id >> 3);
  const int m0 = (swz >> 4) * 256;
  const int n0 = (swz & 15) * 256;
  const int wrow = (wv >> 1) * 64;   // 4 waves down
  const int wcol = (wv & 1) * 128;   // 2 waves across (full head-half per wave)

  const char* Ag = (const char*)A + (size_t)(m0 + wv * 8 + lrow) * 4096 + scol;
  const char* Bg = (const char*)B + (size_t)(n0 + wv * 8 + lrow) * 4096 + scol;
  char* const ldsW = (char*)lds + wv * 1024;  // wave-uniform LDS staging base

  const int csw0 = (quad << 4) ^ ((l16 & 7) << 4);  // swizzled read col, ks=0
  const int csw1 = csw0 ^ 64;                       // ks=1 (bit6 flip commutes w/ XOR)

  floatx4 acc[4][8] = {};
  bf16x8 af[4][2], bfr[8][2];

#define STAGE_A256(kt, buf) { \
    const char* s_ = Ag + (size_t)(kt) * 128; \
    char* d_ = ldsW + (buf) * 65536; \
    async_load16(s_, d_); \
    async_load16(s_ + (size_t)64 * 4096, d_ + 64 * 128); \
    async_load16(s_ + (size_t)128 * 4096, d_ + 128 * 128); \
    async_load16(s_ + (size_t)192 * 4096, d_ + 192 * 128); }
#define STAGE_B256(kt, buf) { \
    const char* s_ = Bg + (size_t)(kt) * 128; \
    char* d_ = ldsW + (buf) * 65536 + 32768; \
    async_load16(s_, d_); \
    async_load16(s_ + (size_t)64 * 4096, d_ + 64 * 128); \
    async_load16(s_ + (size_t)128 * 4096, d_ + 128 * 128); \
    async_load16(s_ + (size_t)192 * 4096, d_ + 192 * 128); }
#define READ_A256(I) { \
    const char* p_ = cA + (wrow + (I) * 16 + l16) * 128; \
    af[I][0] = *(const bf16x8*)(p_ + csw0); \
    af[I][1] = *(const bf16x8*)(p_ + csw1); }
#define READ_B256(J) { \
    const char* p_ = cB + (wcol + (J) * 16 + l16) * 128; \
    bfr[J][0] = *(const bf16x8*)(p_ + csw0); \
    bfr[J][1] = *(const bf16x8*)(p_ + csw1); }
#define MFMA_Q256(I0, J0) { \
    _Pragma("unroll") for (int ks = 0; ks < 2; ++ks) \
    _Pragma("unroll") for (int di = 0; di < 2; ++di) \
    _Pragma("unroll") for (int dj = 0; dj < 4; ++dj) \
      acc[(I0) + di][(J0) + dj] = __builtin_amdgcn_mfma_f32_16x16x32_bf16( \
          af[(I0) + di][ks], bfr[(J0) + dj][ks], acc[(I0) + di][(J0) + dj], 0, 0, 0); }

  // prologue: stage tile0 -> buf0, tile1 -> buf1; wait tile0 (8 newest in flight)
  STAGE_A256(0, 0) STAGE_B256(0, 0)
  STAGE_A256(1, 1) STAGE_B256(1, 1)
  asm volatile("s_waitcnt vmcnt(8)" ::: "memory");
  __builtin_amdgcn_s_barrier();

  const int NT = 32;  // K=2048 / BK=64
  for (int t = 0; t < NT; ++t) {
    const char* cA = (const char*)lds + (t & 1) * 65536;
    const char* cB = cA + 32768;
    // ---- P0: quadrant (rows 0-1, cols 0-3)
    READ_A256(0) READ_A256(1)
    READ_B256(0) READ_B256(1) READ_B256(2) READ_B256(3)
    __builtin_amdgcn_s_barrier();
    asm volatile("s_waitcnt lgkmcnt(0)" ::: "memory");
    __builtin_amdgcn_sched_barrier(0);
    __builtin_amdgcn_s_setprio(1);
    MFMA_Q256(0, 0)
    __builtin_amdgcn_s_setprio(0);
    __builtin_amdgcn_s_barrier();
    // ---- P1: quadrant (rows 2-3, cols 0-3)
    READ_A256(2) READ_A256(3)
    READ_B256(4) READ_B256(5) READ_B256(6) READ_B256(7)
    __builtin_amdgcn_s_barrier();
    asm volatile("s_waitcnt lgkmcnt(0)" ::: "memory");
    __builtin_amdgcn_sched_barrier(0);
    __builtin_amdgcn_s_setprio(1);
    MFMA_Q256(2, 0)
    __builtin_amdgcn_s_setprio(0);
    __builtin_amdgcn_s_barrier();
    // all reads of buffer (t&1) are drained (lgkmcnt(0) above) and all waves
    // passed that point (barrier above) -> safe to overwrite it now.
    __builtin_amdgcn_sched_barrier(0);
    asm volatile("" ::: "memory");
    // ---- P2: quadrant (rows 0-1, cols 4-7); issue tile t+2's A halves
    if (t + 2 < NT) { STAGE_A256(t + 2, t & 1) }
    __builtin_amdgcn_s_setprio(1);
    MFMA_Q256(0, 4)
    __builtin_amdgcn_s_setprio(0);
    __builtin_amdgcn_s_barrier();
    // ---- P3: quadrant (rows 2-3, cols 4-7); issue tile t+2's B halves
    if (t + 2 < NT) { STAGE_B256(t + 2, t & 1) }
    __builtin_amdgcn_s_setprio(1);
    MFMA_Q256(2, 4)
    __builtin_amdgcn_s_setprio(0);
    // boundary: wait tile t+1 landed; keep tile t+2's 8 loads in flight
    if (t + 2 < NT) {
      asm volatile("s_waitcnt vmcnt(8)" ::: "memory");
    } else {
      asm volatile("s_waitcnt vmcnt(0)" ::: "memory");
    }
    __builtin_amdgcn_s_barrier();
  }

  // epilogue: RoPE on (d, d+64) pairs (wave strip is a full 128-wide head-half)
  const float sc = ((n0 + wcol) < 2048) ? 0.08838834764831845f : 1.0f;  // 1/sqrt(128) on Q
#pragma unroll
  for (int i = 0; i < 4; ++i) {
#pragma unroll
    for (int r = 0; r < 4; ++r) {
      const int row = m0 + wrow + i * 16 + quad * 4 + r;
      const int p = pos[row];
      const float* cp = cosT + (size_t)p * HD;
      const float* sp = sinT + (size_t)p * HD;
      bf16* Crow = C + (size_t)row * 4096 + n0 + wcol + l16;
#pragma unroll
      for (int j = 0; j < 4; ++j) {
        const int d = j * 16 + l16;
        const float c = cp[d], s = sp[d];
        const float v1 = acc[i][j][r], v2 = acc[i][j + 4][r];
        Crow[j * 16] = __float2bfloat16((v1 * c - v2 * s) * sc);
        Crow[j * 16 + 64] = __float2bfloat16((v2 * c + v1 * s) * sc);
      }
    }
  }
}

// ---------------- flash attention v3: R1 geometry + conflict-free layouts -----
// grid = (B*NH, S/128), 256 threads, 2 blocks/CU (LDS 64KB). Direct-copy
// staging (no reg-hold -> VGPR stays 128, no spill; R2's T14 spilled: unified
// VGPR+AGPR budget is 256/wave at 8 waves/CU and R1 was already at it).
// T2 layouts (verified correct in R2): 256B-stride rows, byte ^= (row&7)<<4,
// applied both-sides (write + read). QK/PV ds_read_b128 now exact 2-way
// (free, m136); R1's pad-136 was ~4-8-way (9.4M conflicts).
// P overlays the K region (barrier between K-consumption and P-write).
// T5 setprio around both MFMA clusters (attn +4-7%, m191).
// Fixed-shift softmax kept: p = exp(s - 12), one butterfly reduce at the end.
__global__ __launch_bounds__(256, 2) void flash_attn(
    const bf16* __restrict__ QK, const bf16* __restrict__ Vt,
    const float* __restrict__ mask, bf16* __restrict__ AO) {
  __shared__ alignas(16) char KP[128 * 256];  // 32KB: K tile [kv][d], then P [q][k]
  __shared__ alignas(16) char Vs[128 * 256];  // 32KB: V^T tile [d][kv]
  const int tid = threadIdx.x;
  const int wv = tid >> 6;
  const int lane = tid & 63;
  const int quad = lane >> 4;
  const int l16 = lane & 15;
  const int b = blockIdx.x >> 4;
  const int h = blockIdx.x & 15;
  const int q0 = blockIdx.y * 128;

  const bf16* Qb = QK + (size_t)(b * S_LEN + q0) * 4096 + h * HD;
  const char* Kb = (const char*)(QK + (size_t)(b * S_LEN) * 4096 + 2048 + h * HD);
  const char* Vb = (const char*)(Vt + (size_t)(h * HD) * 4096 + (size_t)b * S_LEN);
  const float* Mb = mask + b * S_LEN;

  const int kswz = (l16 & 7) << 4;  // read-side row swizzle (row&7 == l16&7)

  // Q fragments in registers for the whole kernel. A layout: A[m=l16][k=quad*8+j]
  bf16x8 qf[2][4];
#pragma unroll
  for (int s = 0; s < 2; s++)
#pragma unroll
    for (int kc = 0; kc < 4; kc++)
      qf[s][kc] = *(const bf16x8*)(Qb + (size_t)(wv * 32 + s * 16 + l16) * 4096 +
                                   kc * 32 + quad * 8);

  float l_i[2][4] = {};
  floatx4 O[2][8] = {};

  for (int k0 = 0; k0 < S_LEN; k0 += 128) {
    // stage K tile [128 kv][128 d] and V^T tile [128 d][128 kv], swizzled rows
    for (int i = tid; i < 2048; i += 256) {
      const int r = i >> 4;
      const int c16 = (i & 15) * 16;
      const int d_ = r * 256 + (c16 ^ ((r & 7) << 4));
      *(uint4*)(KP + d_) = *(const uint4*)(Kb + (size_t)(k0 + r) * 8192 + c16);
      *(uint4*)(Vs + d_) = *(const uint4*)(Vb + (size_t)r * 8192 + k0 * 2 + c16);
    }
    __syncthreads();

    // QK^T: Sa[strip][ct] is 16x16, rows = q, cols = k_pos
    floatx4 Sa[2][8] = {};
    __builtin_amdgcn_s_setprio(1);
#pragma unroll
    for (int ct = 0; ct < 8; ct++) {
      bf16x8 kf[4];
#pragma unroll
      for (int kc = 0; kc < 4; kc++)
        kf[kc] = *(const bf16x8*)(KP + (ct * 16 + l16) * 256 +
                                  ((kc * 64 + quad * 16) ^ kswz));
#pragma unroll
      for (int s = 0; s < 2; s++)
#pragma unroll
        for (int kc = 0; kc < 4; kc++)
          Sa[s][ct] = __builtin_amdgcn_mfma_f32_16x16x32_bf16(qf[s][kc], kf[kc], Sa[s][ct], 0, 0, 0);
    }
    __builtin_amdgcn_s_setprio(0);
    __syncthreads();  // all K reads done before P overwrites KP

    // mask bias with fixed shift folded in
    float addv[8];
#pragma unroll
    for (int ct = 0; ct < 8; ct++)
      addv[ct] = (1.0f - Mb[k0 + ct * 16 + l16]) * -10000.0f - 12.0f;

    // softmax-lite: p = exp(s + addv); write P (swizzled rows, element k at
    // byte (k*2)^((q&7)<<4) -- matches the pa read below exactly)
#pragma unroll
    for (int s = 0; s < 2; s++) {
#pragma unroll
      for (int r = 0; r < 4; r++) {
        const int lr = wv * 32 + s * 16 + quad * 4 + r;
        char* prow = KP + lr * 256;
        const int rsw = (lr & 7) << 4;
#pragma unroll
        for (int ct = 0; ct < 8; ct++) {
          float p = __expf(Sa[s][ct][r] + addv[ct]);
          l_i[s][r] += p;
          *(bf16*)(prow + ((ct * 32 + l16 * 2) ^ rsw)) = __float2bfloat16(p);
        }
      }
    }

    // PV: O[q][d] += P[q][k] * V[k][d]; A-frags from own wave's P rows
    __builtin_amdgcn_s_setprio(1);
#pragma unroll
    for (int kc = 0; kc < 4; kc++) {
      bf16x8 pa[2];
#pragma unroll
      for (int s = 0; s < 2; s++)
        pa[s] = *(const bf16x8*)(KP + (wv * 32 + s * 16 + l16) * 256 +
                                 ((kc * 64 + quad * 16) ^ kswz));
#pragma unroll
      for (int dt = 0; dt < 8; dt++) {
        bf16x8 vf = *(const bf16x8*)(Vs + (dt * 16 + l16) * 256 +
                                     ((kc * 64 + quad * 16) ^ kswz));
#pragma unroll
        for (int s = 0; s < 2; s++)
          O[s][dt] = __builtin_amdgcn_mfma_f32_16x16x32_bf16(pa[s], vf, O[s][dt], 0, 0, 0);
      }
    }
    __builtin_amdgcn_s_setprio(0);
    __syncthreads();  // PV reads done before next staging overwrites KP/Vs
  }

  // one-time cross-lane reduction of l over the 16 k-lanes (l16 bits 1,2,4,8)
#pragma unroll
  for (int s = 0; s < 2; s++)
#pragma unroll
    for (int r = 0; r < 4; r++)
#pragma unroll
      for (int off = 1; off < 16; off <<= 1)
        l_i[s][r] += __shfl_xor(l_i[s][r], off);

  // epilogue: O /= l, write AO [b, s, h*128+d] (stride H_DIM)
#pragma unroll
  for (int s = 0; s < 2; s++) {
    const int qrow = q0 + wv * 32 + s * 16 + quad * 4;
#pragma unroll
    for (int r = 0; r < 4; r++) {
      float inv = 1.0f / l_i[s][r];
      bf16* outp = AO + (size_t)(b * S_LEN + qrow + r) * H_DIM + h * HD + l16;
#pragma unroll
      for (int dt = 0; dt < 8; dt++)
        outp[dt * 16] = __float2bfloat16(O[s][dt][r] * inv);
    }
  }
}

// ---------------- launch ----------------
extern "C" void kernel_launch(void* const* d_in, const int* in_sizes, int n_in,
                              void* d_out, int out_size, void* d_ws, size_t ws_size,
                              hipStream_t stream) {
  const float* hs   = (const float*)d_in[0];
  const float* wq   = (const float*)d_in[1];
  const float* wk   = (const float*)d_in[2];
  const float* wv   = (const float*)d_in[3];
  const float* wo   = (const float*)d_in[4];
  const float* cosT = (const float*)d_in[5];
  const float* sinT = (const float*)d_in[6];
  const float* mask = (const float*)d_in[7];
  const int*   pos  = (const int*)d_in[8];

  char* ws = (char*)d_ws;
  // workspace layout (96 MB total)
  bf16* Xbf  = (bf16*)ws;                        // [4096,2048] 16MB (reused as AO)
  bf16* Wqkb = (bf16*)(ws + (size_t)(16 << 20)); // [4096,2048] 16MB (Wq rows 0..2047, Wk rows 2048..)
  bf16* Wvb  = (bf16*)(ws + (size_t)(32 << 20)); // 8MB
  bf16* Wob  = (bf16*)(ws + (size_t)(40 << 20)); // 8MB
  bf16* QKm  = (bf16*)(ws + (size_t)(48 << 20)); // [4096 tok][4096] 32MB (Q|K, post-RoPE)
  bf16* Vtm  = (bf16*)(ws + (size_t)(80 << 20)); // [2048 feat][4096 tok] 16MB (V^T)
  bf16* AO   = Xbf;                              // attention output aliases Xbf (dead)

  cast_kernel<<<8192, 256, 0, stream>>>(hs, Xbf, 2097152);
  cast4_kernel<<<16384, 256, 0, stream>>>(wq, wk, wv, wo,
                                          Wqkb, Wqkb + (size_t)2048 * 2048, Wvb, Wob);

  // QK = RoPE(X [Wq;Wk]^T) fused; 256^2-tile 4-phase pipelined kernel
  gemm_qk_rope256<<<256, 512, 0, stream>>>(Xbf, Wqkb, QKm, cosT, sinT, pos);
  // Vt = Wv X^T (feature-major)
  gemm_bt<bf16><<<dim3(16, 32), 256, 0, stream>>>(Wvb, Xbf, Vtm, 2048, 4096, 2048);

  flash_attn<<<dim3(32, 16), 256, 0, stream>>>(QKm, Vtm, mask, AO);

  // out = AO Wo^T (fp32 out)
  gemm_bt<float><<<dim3(32, 16), 256, 0, stream>>>(AO, Wob, (float*)d_out, 4096, 2048, 2048);
}